// Round 1
// 79.328 us; speedup vs baseline: 1.1020x; 1.1020x over previous
//
#include <hip/hip_runtime.h>

// Quanv2d: 4-qubit circuit per 2x2 patch. Weights are patch-independent, so
// the circuit reduces to out_q = psi0^T Re(U^dag Z_q U) psi0 with psi0 a real
// product state. Per-qubit factorization -> 81-coeff tensor contraction.
// Round 2: basis change u_q = A . (1, sin a, cos a) folded into the coeff
// tensor at setup, so the main kernel needs only 8 muls + 320 FMAs per patch.
// Round 3 (this round): setup parallelized. The CRZ diagonal phases and RY
// angles are column-independent -> only 40 distinct sincos in the whole
// circuit. Lanes 0..39 build trig tables once; then all 256 threads evolve
// one amplitude U[m][j] each (thread=(j=tid>>4, m=tid&15)): CRZ = per-thread
// complex mul by shared phase, RY = shfl_xor(stride in {8,4,2,1}) + 2 FMA.
// Removes the old 16-active-lane serial evolution with 640 redundant libm
// sincos calls on the critical path of a 1-block kernel.

static __device__ __forceinline__ int bit_of(int m, int q) { return (m >> (3 - q)) & 1; }

__global__ __launch_bounds__(256) void quanv_setup(const float* __restrict__ w,
                                                   float* __restrict__ Dout) {
    __shared__ float Ur[16][16], Ui[16][16];
    __shared__ float Cs[324], Ts[324];
    __shared__ float crz_c[2][16], crz_s[2][16];
    __shared__ float ry_c[2][4], ry_s[2][4];
    const int tid = threadIdx.x;
    for (int i0 = tid; i0 < 324; i0 += 256) Cs[i0] = 0.f;

    // --- distinct trig values: 2 layers x (16 CRZ phases + 4 RY half-angles) ---
    if (tid < 32) {
        const int layer = tid >> 4, m = tid & 15;
        // fused CRZ diagonal phase: CRZ(phi) on (control=q, target=(q+1)%4)
        float th = 0.f;
        for (int q = 0; q < 4; ++q)
            if (bit_of(m, q)) th += w[layer * 8 + q] * (bit_of(m, (q + 1) & 3) ? 0.5f : -0.5f);
        sincosf(th, &crz_s[layer][m], &crz_c[layer][m]);
    } else if (tid < 40) {
        const int layer = (tid - 32) >> 2, q = tid & 3;
        sincosf(w[layer * 8 + 4 + q] * 0.5f, &ry_s[layer][q], &ry_c[layer][q]);
    }
    __syncthreads();

    // --- evolve basis column j: thread (j, m) holds amplitude U[m][j] ---
    {
        const int j = tid >> 4, m = tid & 15;
        float ar = (m == j) ? 1.f : 0.f, ai = 0.f;
#pragma unroll
        for (int layer = 0; layer < 2; ++layer) {
            // CRZ diagonal: multiply by e^{i th_m}
            const float cs = crz_c[layer][m], sn = crz_s[layer][m];
            const float r = ar * cs - ai * sn;
            ai = ar * sn + ai * cs;
            ar = r;
            // RY on wire q: pair (m, m^stride); lane^stride stays in the same
            // 16-lane m-group (stride <= 8), so j is preserved across the shuffle.
#pragma unroll
            for (int q = 0; q < 4; ++q) {
                const int stride = 8 >> q;  // wire q is bit (3-q)
                const float ct = ry_c[layer][q], st = ry_s[layer][q];
                const float sgn = (m & stride) ? st : -st;  // v0'=c*v0-s*v1 ; v1'=s*v0+c*v1
                const float pr = __shfl_xor(ar, stride, 64);
                const float pi_ = __shfl_xor(ai, stride, 64);
                ar = fmaf(sgn, pr, ct * ar);
                ai = fmaf(sgn, pi_, ct * ai);
            }
        }
        Ur[m][j] = ar;
        Ui[m][j] = ai;
    }
    __syncthreads();

    {
        // M_q[j][k] = sum_m Z_q[m] (Ur[m][j]Ur[m][k] + Ui[m][j]Ui[m][k])
        const int j = tid >> 4, k = tid & 15;
        float a0 = 0.f, a1 = 0.f, a2 = 0.f, a3 = 0.f;
        for (int m = 0; m < 16; ++m) {
            float s = Ur[m][j] * Ur[m][k] + Ui[m][j] * Ui[m][k];
            a0 += bit_of(m, 0) ? -s : s;
            a1 += bit_of(m, 1) ? -s : s;
            a2 += bit_of(m, 2) ? -s : s;
            a3 += bit_of(m, 3) ? -s : s;
        }
        int bin = 0;
        for (int q = 0; q < 4; ++q) bin = bin * 3 + bit_of(j, q) + bit_of(k, q);
        atomicAdd(&Cs[bin * 4 + 0], a0);
        atomicAdd(&Cs[bin * 4 + 1], a1);
        atomicAdd(&Cs[bin * 4 + 2], a2);
        atomicAdd(&Cs[bin * 4 + 3], a3);
    }
    __syncthreads();

    // Basis change per qubit axis: D[b] = sum_a A[a][b] C[a], with
    // u0=(1-s)/2, u1=c/2, u2=(1+s)/2 => A rows: a0=(.5,-.5,0) a1=(0,0,.5) a2=(.5,.5,0)
    // sweep j transforms base-3 digit j (place value 27,9,3,1); ping-pong Cs<->Ts
#pragma unroll
    for (int j = 0; j < 4; ++j) {
        const int pv = (j == 0) ? 27 : (j == 1) ? 9 : (j == 2) ? 3 : 1;
        const float* src = (j & 1) ? Ts : Cs;
        float*       dst = (j & 1) ? Cs : Ts;
        for (int e = tid; e < 324; e += 256) {
            int bin = e >> 2, qo = e & 3;
            int d = (bin / pv) % 3;
            int base = bin - d * pv;
            float i0 = src[(base         ) * 4 + qo];
            float i1 = src[(base +     pv) * 4 + qo];
            float i2 = src[(base + 2 * pv) * 4 + qo];
            dst[e] = (d == 0) ? 0.5f * (i0 + i2)
                   : (d == 1) ? 0.5f * (i2 - i0)
                              : 0.5f * i1;
        }
        __syncthreads();
    }
    for (int i0 = tid; i0 < 324; i0 += 256) Dout[i0] = Cs[i0];  // after 4 sweeps result is back in Cs
}

// One thread per patch. D accesses are wave-uniform -> scalar loads feeding
// v_fma_f32 with an SGPR operand. Inner contraction: two-level Horner over
// (b23, b01) with b[0]==1 levels free: 8 muls + 320 FMAs.
__global__ __launch_bounds__(256) void quanv_main(const float2* __restrict__ x2,
                                                  const float* __restrict__ D,
                                                  float4* __restrict__ out) {
    const int tid = blockIdx.x * 256 + threadIdx.x;
    const int b = tid >> 12;          // 4096 patches per image
    const int p = tid & 4095;
    const int pi = p >> 6, pj = p & 63;
    const float2* row = x2 + (size_t)b * 8192 + (size_t)(2 * pi) * 64 + pj;
    float2 a01 = row[0];    // x[b, 2i, 2j], x[b, 2i, 2j+1]
    float2 a23 = row[64];   // x[b, 2i+1, 2j], x[b, 2i+1, 2j+1]

    float s0, c0, s1, c1, s2, c2, s3, c3;
    __sincosf(a01.x, &s0, &c0);
    __sincosf(a01.y, &s1, &c1);
    __sincosf(a23.x, &s2, &c2);
    __sincosf(a23.y, &s3, &c3);

    // rank-1 products in the (1, sin, cos) basis; index = b_hi*3 + b_lo
    float P01[9], P23[9];
    P01[1] = s1;      P01[2] = c1;      P01[3] = s0;      P01[6] = c0;
    P01[4] = s0 * s1; P01[5] = s0 * c1; P01[7] = c0 * s1; P01[8] = c0 * c1;
    P23[1] = s3;      P23[2] = c3;      P23[3] = s2;      P23[6] = c2;
    P23[4] = s2 * s3; P23[5] = s2 * c3; P23[7] = c2 * s3; P23[8] = c2 * c3;

    float o0, o1, o2, o3;
#pragma unroll
    for (int b01 = 0; b01 < 9; ++b01) {
        const float* Db = D + b01 * 36;              // D[(b01*9 + b23)*4 + q]
        float g0 = Db[0], g1 = Db[1], g2 = Db[2], g3 = Db[3];  // b23 = 0 term (P23[0]==1)
#pragma unroll
        for (int b23 = 1; b23 < 9; ++b23) {
            float pq = P23[b23];
            g0 = fmaf(Db[b23 * 4 + 0], pq, g0);
            g1 = fmaf(Db[b23 * 4 + 1], pq, g1);
            g2 = fmaf(Db[b23 * 4 + 2], pq, g2);
            g3 = fmaf(Db[b23 * 4 + 3], pq, g3);
        }
        if (b01 == 0) { o0 = g0; o1 = g1; o2 = g2; o3 = g3; }  // P01[0]==1
        else {
            float pp = P01[b01];
            o0 = fmaf(g0, pp, o0); o1 = fmaf(g1, pp, o1);
            o2 = fmaf(g2, pp, o2); o3 = fmaf(g3, pp, o3);
        }
    }
    out[tid] = make_float4(o0, o1, o2, o3);
}

extern "C" void kernel_launch(void* const* d_in, const int* in_sizes, int n_in,
                              void* d_out, int out_size, void* d_ws, size_t ws_size,
                              hipStream_t stream) {
    const float* x = (const float*)d_in[0];
    const float* w = (const float*)d_in[1];
    float* Dt = (float*)d_ws;            // 324 floats of scratch
    float4* outv = (float4*)d_out;

    quanv_setup<<<1, 256, 0, stream>>>(w, Dt);

    const int n_patches = in_sizes[0] / 4;       // B * 64 * 64
    quanv_main<<<n_patches / 256, 256, 0, stream>>>((const float2*)x, Dt, outv);
}